// Round 1
// baseline (460.746 us; speedup 1.0000x reference)
//
#include <hip/hip_runtime.h>
#include <hip/hip_bf16.h>

// 3D conv, K=2, VALID, stride 1, then (y+1)^2.
// x: (8, 16, 64, 64, 64) f32;  w: (32, 128) f32 where 128 = c*8+kd*4+kh*2+kw
// out: (8, 32, 63, 63, 63) f32
//
// One thread per output spatial position (b,d,h,w), accumulating all 32
// output channels in registers. Weight indices are wave-uniform -> scalar
// loads (SGPR broadcast). x loads coalesced along w, reused via L1.

#define C_IN 16
#define O_OUT 32
#define DIN 64
#define DOUT 63

__global__ __launch_bounds__(256) void conv3d_k2_poly(
    const float* __restrict__ x,
    const float* __restrict__ wgt,
    float* __restrict__ out)
{
    const int wi   = threadIdx.x & 63;          // w position (0..63, 63 inactive)
    const int hsub = threadIdx.x >> 6;          // 0..3
    const int h    = blockIdx.x * 4 + hsub;     // 0..63 (63 inactive)
    const int d    = blockIdx.y;                // 0..62
    const int b    = blockIdx.z;                // 0..7

    if (wi >= DOUT || h >= DOUT) return;

    const size_t x_cstride = (size_t)DIN * DIN * DIN;        // 262144
    const float* xb = x + (size_t)b * C_IN * x_cstride
                        + (size_t)d * (DIN * DIN)
                        + (size_t)h * DIN
                        + wi;

    float acc[O_OUT];
#pragma unroll
    for (int o = 0; o < O_OUT; ++o) acc[o] = 0.0f;

    for (int c = 0; c < C_IN; ++c) {
        // load the 2x2x2 input taps for this channel
        float xv[8];
#pragma unroll
        for (int kd = 0; kd < 2; ++kd)
#pragma unroll
            for (int kh = 0; kh < 2; ++kh)
#pragma unroll
                for (int kw = 0; kw < 2; ++kw)
                    xv[kd * 4 + kh * 2 + kw] =
                        xb[(size_t)c * x_cstride + (size_t)kd * (DIN * DIN) + kh * DIN + kw];

#pragma unroll
        for (int o = 0; o < O_OUT; ++o) {
            const float* wp = wgt + o * 128 + c * 8;   // uniform address -> s_load
            float a = acc[o];
#pragma unroll
            for (int t = 0; t < 8; ++t)
                a = fmaf(xv[t], wp[t], a);
            acc[o] = a;
        }
    }

    const size_t o_stride = (size_t)DOUT * DOUT * DOUT;      // 250047
    float* ob = out + (size_t)b * O_OUT * o_stride
                    + (size_t)d * (DOUT * DOUT)
                    + (size_t)h * DOUT
                    + wi;
#pragma unroll
    for (int o = 0; o < O_OUT; ++o) {
        float y = acc[o] + 1.0f;
        ob[(size_t)o * o_stride] = y * y;
    }
}

extern "C" void kernel_launch(void* const* d_in, const int* in_sizes, int n_in,
                              void* d_out, int out_size, void* d_ws, size_t ws_size,
                              hipStream_t stream) {
    const float* x   = (const float*)d_in[0];
    const float* wgt = (const float*)d_in[1];
    float* out = (float*)d_out;

    // grid: x = ceil(63/4)=16 h-tiles, y = 63 d, z = 8 b; block = 256 (4 h-rows x 64 w)
    dim3 grid(16, DOUT, 8);
    dim3 block(256);
    conv3d_k2_poly<<<grid, block, 0, stream>>>(x, wgt, out);
}

// Round 2
// 251.349 us; speedup vs baseline: 1.8331x; 1.8331x over previous
//
#include <hip/hip_runtime.h>
#include <hip/hip_bf16.h>

// 3D conv K=2 VALID + (y+1)^2 as bf16 MFMA GEMM.
// x: (8,16,64,64,64) f32; w: (32, 128) f32 with k = c*8 + kd*4 + kh*2 + kw.
// out: (8,32,63,63,63) f32.
//
// Block = 256 thr (4 waves), tile = (b, d, 8 h-rows, 64 w). LDS holds the
// bf16 x tile [c=16][kd=2][h=9][w=64], c-stride padded 1152->1168 elems so
// ds_read_u16 fragment reads are bank-conflict-free (c-stride = 584 dwords
// = 8 mod 32 -> each lane-quartet owns its own 8-bank group).
// mfma_f32_16x16x32_bf16: A row = lane&15, k = 8*(lane>>4)+j (j = tap idx,
// so one lane's 8 elems = the 2x2x2 taps of one channel); D col = lane&15
// (w), row = 4*(lane>>4)+reg (o) [HW-verified mapping].

typedef __attribute__((ext_vector_type(8))) short short8;
typedef __attribute__((ext_vector_type(4))) float f32x4;
typedef __attribute__((ext_vector_type(4))) unsigned short u16x4;

#define CS 1168           // padded c-stride (2*9*64 + 16) in bf16 elems
#define OS 250047         // 63^3, out channel stride
#define XCS 262144        // 64^3, x channel stride

__device__ __forceinline__ unsigned short f2bf(float f) {
    unsigned int u = __builtin_bit_cast(unsigned int, f);
    return (unsigned short)((u + 0x7fffu + ((u >> 16) & 1u)) >> 16);
}

__global__ __launch_bounds__(256) void conv3d_k2_mfma(
    const float* __restrict__ x,
    const float* __restrict__ wgt,
    float* __restrict__ out)
{
    __shared__ unsigned short tile[16 * CS];   // 37,376 B

    const int t  = threadIdx.x;
    const int l  = t & 63;
    const int wv = t >> 6;          // wave 0..3
    const int lw = l & 15;          // col within fragment
    const int lk = l >> 4;          // k-quartet 0..3

    const int h0 = blockIdx.x * 8;  // h-tile base (0..56)
    const int d  = blockIdx.y;      // 0..62
    const int b  = blockIdx.z;      // 0..7

    // ---- A fragments: w[o = m*16+lw][k = s*32 + lk*8 + j] -> bf16 ----
    short8 aF[2][4];
#pragma unroll
    for (int m = 0; m < 2; ++m)
#pragma unroll
        for (int s = 0; s < 4; ++s) {
            const float* wp = wgt + (m * 16 + lw) * 128 + s * 32 + lk * 8;
            f32x4 w0 = *(const f32x4*)wp;
            f32x4 w1 = *(const f32x4*)(wp + 4);
            short8 a;
#pragma unroll
            for (int j = 0; j < 4; ++j) {
                a[j]     = (short)f2bf(w0[j]);
                a[j + 4] = (short)f2bf(w1[j]);
            }
            aF[m][s] = a;
        }

    // ---- stage x tile: rows (c,kd,hh), 16 lanes x float4 per row ----
    const float* xb = x + (size_t)b * 16 * XCS;
    const int lane16 = t & 15;
    const int rsub   = t >> 4;      // 16 rows per iteration
#pragma unroll
    for (int i = 0; i < 18; ++i) {
        int R   = i * 16 + rsub;    // 0..287
        int c   = R / 18;
        int rem = R - c * 18;
        int kd  = rem / 9;
        int hh  = rem - kd * 9;
        int hp  = h0 + hh; if (hp > 63) hp = 63;     // clamp (masked rows)
        const float* src = xb + (size_t)c * XCS + (size_t)(d + kd) * 4096
                              + hp * 64 + 4 * lane16;
        f32x4 v = *(const f32x4*)src;
        u16x4 p;
#pragma unroll
        for (int j = 0; j < 4; ++j) p[j] = f2bf(v[j]);
        *(u16x4*)&tile[c * CS + kd * 576 + hh * 64 + 4 * lane16] = p;
    }
    __syncthreads();

    // ---- compute: 8 position-groups per wave (2 h-rows x 4 w-groups) ----
#pragma unroll
    for (int g = 0; g < 8; ++g) {
        const int hl = wv * 2 + (g >> 2);   // local h row 0..7
        const int wb = (g & 3) * 16;        // w base 0,16,32,48
        f32x4 acc0 = {0.f, 0.f, 0.f, 0.f};
        f32x4 acc1 = {0.f, 0.f, 0.f, 0.f};
#pragma unroll
        for (int s = 0; s < 4; ++s) {
            const int c = s * 4 + lk;
            const int base = c * CS + hl * 64 + wb + lw;
            short8 bf;
            bf[0] = (short)tile[base + 0];     // kd0 kh0 kw0
            bf[1] = (short)tile[base + 1];     // kd0 kh0 kw1
            bf[2] = (short)tile[base + 64];    // kd0 kh1 kw0
            bf[3] = (short)tile[base + 65];
            bf[4] = (short)tile[base + 576];   // kd1 kh0 kw0
            bf[5] = (short)tile[base + 577];
            bf[6] = (short)tile[base + 640];   // kd1 kh1 kw0
            bf[7] = (short)tile[base + 641];
            acc0 = __builtin_amdgcn_mfma_f32_16x16x32_bf16(aF[0][s], bf, acc0, 0, 0, 0);
            acc1 = __builtin_amdgcn_mfma_f32_16x16x32_bf16(aF[1][s], bf, acc1, 0, 0, 0);
        }
        const int h  = h0 + hl;
        const int wc = wb + lw;
        if (h < 63 && wc < 63) {
            float* ob = out + (size_t)b * 32 * OS + (size_t)d * 3969 + h * 63 + wc;
#pragma unroll
            for (int r = 0; r < 4; ++r) {
                const int o0 = lk * 4 + r;          // D row = 4*(lane>>4)+reg
                float y0 = acc0[r] + 1.0f;
                ob[(size_t)o0 * OS] = y0 * y0;
                float y1 = acc1[r] + 1.0f;
                ob[(size_t)(o0 + 16) * OS] = y1 * y1;
            }
        }
    }
}

extern "C" void kernel_launch(void* const* d_in, const int* in_sizes, int n_in,
                              void* d_out, int out_size, void* d_ws, size_t ws_size,
                              hipStream_t stream) {
    const float* x   = (const float*)d_in[0];
    const float* wgt = (const float*)d_in[1];
    float* out = (float*)d_out;

    dim3 grid(8, 63, 8);    // h-tiles, d, b
    dim3 block(256);
    conv3d_k2_mfma<<<grid, block, 0, stream>>>(x, wgt, out);
}

// Round 3
// 242.996 us; speedup vs baseline: 1.8961x; 1.0344x over previous
//
#include <hip/hip_runtime.h>
#include <hip/hip_bf16.h>

// 3D conv K=2 VALID + (y+1)^2, bf16 MFMA, d-rolling double-buffered LDS.
// x: (8,16,64,64,64) f32; w: (32,128) f32, k = c*8 + kd*4 + kh*2 + kw.
// out: (8,32,63,63,63) f32.
//
// Block = 256 thr (4 waves) owns (b, 8 h-rows, 4 d-outputs). LDS holds TWO
// d-slabs [c=16][h=9][w=64] bf16 (c-stride padded 576->592 elems == 8 mod 32
// dwords -> conflict-free fragment reads). Each output d uses slab d (kd=0,
// buf d&1) and slab d+1 (kd=1, buf (d+1)&1); slab d+2 is prefetched to regs
// during compute and written to buf d&1 after the barrier (T14 split).
// Every slab is loaded from global exactly once per block: logical reads
// drop ~6.3x vs the per-d staging of round 2.

typedef __attribute__((ext_vector_type(8))) short short8;
typedef __attribute__((ext_vector_type(4))) float f32x4;
typedef __attribute__((ext_vector_type(4))) unsigned short u16x4;

#define XCS 262144        // 64^3 x channel stride (f32 elems)
#define OS  250047        // 63^3 out channel stride
#define CST 592           // LDS c-stride in bf16 elems (9*64=576 + 16 pad)
#define SLAB (16 * CST)   // 9472 elems per slab

__device__ __forceinline__ unsigned short f2bf(float f) {
    unsigned int u = __builtin_bit_cast(unsigned int, f);
    return (unsigned short)((u + 0x7fffu + ((u >> 16) & 1u)) >> 16);
}

__global__ __launch_bounds__(256, 4) void conv3d_k2_roll(
    const float* __restrict__ x,
    const float* __restrict__ wgt,
    float* __restrict__ out)
{
    __shared__ unsigned short tile[2 * SLAB];   // 37,888 B

    const int t  = threadIdx.x;
    const int l  = t & 63;
    const int wv = t >> 6;          // wave 0..3
    const int lw = l & 15;          // fragment col (w within group)
    const int lk = l >> 4;          // k-quartet 0..3

    const int h0 = blockIdx.x * 8;  // 8 output h rows (h0..h0+7)
    const int d0 = blockIdx.y * 4;  // 4 output d (3 for last chunk)
    const int b  = blockIdx.z;
    const int nd = (d0 == 60) ? 3 : 4;

    // ---- A fragments: w[o = m*16+lw][k = s*32 + lk*8 + j] -> bf16 ----
    short8 aF[2][4];
#pragma unroll
    for (int m = 0; m < 2; ++m)
#pragma unroll
        for (int s = 0; s < 4; ++s) {
            const float* wp = wgt + (m * 16 + lw) * 128 + s * 32 + lk * 8;
            f32x4 w0 = *(const f32x4*)wp;
            f32x4 w1 = *(const f32x4*)(wp + 4);
            short8 a;
#pragma unroll
            for (int j = 0; j < 4; ++j) {
                a[j]     = (short)f2bf(w0[j]);
                a[j + 4] = (short)f2bf(w1[j]);
            }
            aF[m][s] = a;
        }

    // ---- staging geometry: thread (sc = c, sl = w-quad) covers 9 h rows ----
    const int sc = t >> 4;          // c 0..15
    const int sl = t & 15;          // 16-B w quad
    const float* xb = x + (size_t)b * 16 * XCS + (size_t)sc * XCS + sl * 4;

    // prologue: stage slabs d0, d0+1
#pragma unroll
    for (int p = 0; p < 2; ++p) {
#pragma unroll
        for (int h = 0; h < 9; ++h) {
            int hp = h0 + h; if (hp > 63) hp = 63;
            f32x4 v = *(const f32x4*)(xb + (size_t)(d0 + p) * 4096 + hp * 64);
            u16x4 pk;
#pragma unroll
            for (int j = 0; j < 4; ++j) pk[j] = f2bf(v[j]);
            *(u16x4*)&tile[p * SLAB + sc * CST + h * 64 + sl * 4] = pk;
        }
    }
    __syncthreads();

    for (int dd = 0; dd < 4; ++dd) {
        if (dd >= nd) break;
        const bool doPre = (dd + 1) < nd;    // next iter needs slab d0+dd+2

        // issue prefetch loads (kept in regs; waitcnt lands after compute)
        f32x4 pre[9];
        if (doPre) {
#pragma unroll
            for (int h = 0; h < 9; ++h) {
                int hp = h0 + h; if (hp > 63) hp = 63;
                pre[h] = *(const f32x4*)(xb + (size_t)(d0 + dd + 2) * 4096 + hp * 64);
            }
        }

        // compute output d = d0+dd from bufs (dd&1)=kd0, ((dd+1)&1)=kd1
        const int pA = (dd & 1) * SLAB;
        const int pB = ((dd + 1) & 1) * SLAB;
#pragma unroll
        for (int g = 0; g < 8; ++g) {
            const int hl = wv * 2 + (g >> 2);   // local h row 0..7
            const int wb = (g & 3) * 16;        // w base
            f32x4 acc0 = {0.f, 0.f, 0.f, 0.f};
            f32x4 acc1 = {0.f, 0.f, 0.f, 0.f};
#pragma unroll
            for (int s = 0; s < 4; ++s) {
                const int c  = s * 4 + lk;
                const int ba = pA + c * CST + hl * 64 + wb + lw;
                const int bb = pB + c * CST + hl * 64 + wb + lw;
                short8 bf;
                bf[0] = (short)tile[ba];        // kd0 kh0 kw0
                bf[1] = (short)tile[ba + 1];
                bf[2] = (short)tile[ba + 64];   // kd0 kh1
                bf[3] = (short)tile[ba + 65];
                bf[4] = (short)tile[bb];        // kd1 kh0
                bf[5] = (short)tile[bb + 1];
                bf[6] = (short)tile[bb + 64];   // kd1 kh1
                bf[7] = (short)tile[bb + 65];
                acc0 = __builtin_amdgcn_mfma_f32_16x16x32_bf16(aF[0][s], bf, acc0, 0, 0, 0);
                acc1 = __builtin_amdgcn_mfma_f32_16x16x32_bf16(aF[1][s], bf, acc1, 0, 0, 0);
            }
            const int h  = h0 + hl;
            const int wc = wb + lw;
            if (h < 63 && wc < 63) {
                float* ob = out + (size_t)b * 32 * OS + (size_t)(d0 + dd) * 3969
                                + h * 63 + wc;
#pragma unroll
                for (int r = 0; r < 4; ++r) {
                    const int o0 = lk * 4 + r;  // D row = 4*(lane>>4)+reg
                    float y0 = acc0[r] + 1.0f;
                    ob[(size_t)o0 * OS] = y0 * y0;
                    float y1 = acc1[r] + 1.0f;
                    ob[(size_t)(o0 + 16) * OS] = y1 * y1;
                }
            }
        }

        __syncthreads();                    // all waves done reading buf dd&1
        if (doPre) {
#pragma unroll
            for (int h = 0; h < 9; ++h) {
                u16x4 pk;
#pragma unroll
                for (int j = 0; j < 4; ++j) pk[j] = f2bf(pre[h][j]);
                *(u16x4*)&tile[(dd & 1) * SLAB + sc * CST + h * 64 + sl * 4] = pk;
            }
        }
        __syncthreads();
    }
}

extern "C" void kernel_launch(void* const* d_in, const int* in_sizes, int n_in,
                              void* d_out, int out_size, void* d_ws, size_t ws_size,
                              hipStream_t stream) {
    const float* x   = (const float*)d_in[0];
    const float* wgt = (const float*)d_in[1];
    float* out = (float*)d_out;

    dim3 grid(8, 16, 8);    // h-tiles, d-chunks, b
    dim3 block(256);
    conv3d_k2_roll<<<grid, block, 0, stream>>>(x, wgt, out);
}

// Round 4
// 139.544 us; speedup vs baseline: 3.3018x; 1.7414x over previous
//
#include <hip/hip_runtime.h>
#include <hip/hip_bf16.h>

// 3D conv K=2 VALID + (y+1)^2 via mfma_f32_32x32x16_bf16.
// x: (8,16,64,64,64) f32; w: (32,128) f32, k = c*8 + kd*4 + kh*2 + kw.
// out: (8,32,63,63,63) f32.
//
// GEMM K-order permuted to k' = tap*16 + c: each MFMA (K=16) consumes ONE
// tap's 16 channels. B-fragment lane layout (n = lane&31 = w, k-half =
// lane>>5 = c-half) then matches an LDS tile laid out [h][w][c16] bf16:
// one ds_read_b128 per fragment (64 lanes read 1024 contiguous B -> bank-
// uniform). D cols = 32-lane w-runs -> stores are 128-B full-line segments
// (fixes the 1.44x write amplification seen in R2/R3). M=32 = all o in one
// 16-reg acc; 8 MFMAs per 32x32 output tile.
//
// Staging transposes c into the lane: thread (w = t&63, cq = t>>6) loads 4
// scalar f32 from 4 c-planes (each instr = one 256-B segment) and writes
// one u16x4 to LDS (4-way bank conflict, staging only - cheap).

typedef __attribute__((ext_vector_type(8)))  short short8;
typedef __attribute__((ext_vector_type(16))) float f32x16;
typedef __attribute__((ext_vector_type(4)))  unsigned short u16x4;

#define XCS 262144        // 64^3 x channel stride (f32)
#define OS  250047        // 63^3 out channel stride (f32)
#define SLAB_E 9216       // 9*64*16 u16 per d-slab

__device__ __forceinline__ unsigned short f2bf(float f) {
    unsigned int u = __builtin_bit_cast(unsigned int, f);
    return (unsigned short)((u + 0x7fffu + ((u >> 16) & 1u)) >> 16);
}

__global__ __launch_bounds__(256, 4) void conv3d_k2_mfma32(
    const float* __restrict__ x,
    const float* __restrict__ wgt,
    float* __restrict__ out)
{
    __shared__ unsigned short tile[2 * SLAB_E + 32];   // 36,928 B (+OOB pad)

    const int t   = threadIdx.x;
    const int l   = t & 63;
    const int wv  = t >> 6;        // wave 0..3
    const int col = l & 31;        // MFMA col (w) / A row (o)
    const int kh8 = l >> 5;        // k-half -> c-half

    const int h0 = blockIdx.x * 8; // 8 output h rows
    const int d  = blockIdx.y;     // 0..62
    const int b  = blockIdx.z;

    // ---- A fragments: aF[tap][j] = w[o = col][c = kh8*8+j][tap] ----
    short8 aF[8];
#pragma unroll
    for (int tap = 0; tap < 8; ++tap) {
        short8 a;
#pragma unroll
        for (int j = 0; j < 8; ++j)
            a[j] = (short)f2bf(wgt[col * 128 + (kh8 * 8 + j) * 8 + tap]);
        aF[tap] = a;
    }

    // ---- stage slabs d, d+1 into [h9][w64][c16] bf16 ----
    {
        const int sw = t & 63;     // w (full row per instr -> 256-B segments)
        const int cq = t >> 6;     // c quad 0..3
#pragma unroll
        for (int sl = 0; sl < 2; ++sl) {
            const float* xs = x + (size_t)b * 16 * XCS + (size_t)(d + sl) * 4096;
#pragma unroll
            for (int h = 0; h < 9; ++h) {
                int hp = h0 + h; if (hp > 63) hp = 63;   // clamp (masked rows)
                u16x4 p;
#pragma unroll
                for (int i = 0; i < 4; ++i)
                    p[i] = f2bf(xs[(size_t)(cq * 4 + i) * XCS + hp * 64 + sw]);
                *(u16x4*)&tile[sl * SLAB_E + h * 1024 + sw * 16 + cq * 4] = p;
            }
        }
    }
    __syncthreads();

    // ---- compute: wave owns h rows {wv*2, wv*2+1} x w-halves {0,32} ----
#pragma unroll
    for (int th = 0; th < 2; ++th) {
        const int hl = wv * 2 + th;
#pragma unroll
        for (int wh = 0; wh < 2; ++wh) {
            const int wb = wh * 32;
            f32x16 acc = {};
#pragma unroll
            for (int kd = 0; kd < 2; ++kd)
#pragma unroll
            for (int kh = 0; kh < 2; ++kh)
#pragma unroll
            for (int kw = 0; kw < 2; ++kw) {
                const int tap = kd * 4 + kh * 2 + kw;
                // one b128: 8 consecutive bf16 (c = kh8*8 .. +7)
                short8 bfrag = *(const short8*)&tile[kd * SLAB_E
                    + (hl + kh) * 1024 + (wb + col + kw) * 16 + kh8 * 8];
                acc = __builtin_amdgcn_mfma_f32_32x32x16_bf16(aF[tap], bfrag, acc, 0, 0, 0);
            }
            const int h  = h0 + hl;
            const int wc = wb + col;
            if (h < 63 && wc < 63) {
                float* ob = out + (size_t)b * 32 * OS + (size_t)d * 3969
                                + h * 63 + wc;
#pragma unroll
                for (int r = 0; r < 16; ++r) {
                    const int o = (r & 3) + 8 * (r >> 2) + 4 * kh8;  // D row map
                    float y = acc[r] + 1.0f;
                    ob[(size_t)o * OS] = y * y;
                }
            }
        }
    }
}

extern "C" void kernel_launch(void* const* d_in, const int* in_sizes, int n_in,
                              void* d_out, int out_size, void* d_ws, size_t ws_size,
                              hipStream_t stream) {
    const float* x   = (const float*)d_in[0];
    const float* wgt = (const float*)d_in[1];
    float* out = (float*)d_out;

    dim3 grid(8, 63, 8);    // h-tiles, d, b
    dim3 block(256);
    conv3d_k2_mfma32<<<grid, block, 0, stream>>>(x, wgt, out);
}